// Round 5
// baseline (143.431 us; speedup 1.0000x reference)
//
#include <hip/hip_runtime.h>
#include <hip/hip_bf16.h>

typedef __bf16 bf16x8 __attribute__((ext_vector_type(8)));
typedef float f32x4 __attribute__((ext_vector_type(4)));
typedef float f32x16 __attribute__((ext_vector_type(16)));
typedef unsigned int u32;

// ws layout (bytes):
//   [0,        524288)  WtF   : bf16 W_enc^T frag-major [nc=16][f=32][lane=64][e=8]
//   [524288,   655360)  bias2p: f32 [64][512]  (attn2 + b_dec + b_enc)
//   [655360,   917504)  logits: f32 [65536]
//   [917504,  1966080)  part  : f32 [64][8][512]
#define WS_WT     0
#define WS_BIAS   524288
#define WS_LOGITS 655360
#define WS_PART   917504

__device__ __forceinline__ unsigned short f2bf(float f) {
    __bf16 h = (__bf16)f;
    return __builtin_bit_cast(unsigned short, h);
}

// K0a: frag-major pack of W_enc for mfma_32x32x16 B-operand.
// WtF flat idx = ((nc*32 + f)*64 + l)*8 + e  -> value W_enc[k][n],
// n = nc*32 + (l&31), k = f*16 + (l>>5)*8 + e.
__global__ void k_wt(const float* __restrict__ W, unsigned short* __restrict__ WtF) {
    int u = (blockIdx.x * 256 + threadIdx.x) * 4;
    #pragma unroll
    for (int i = 0; i < 4; ++i) {
        int idx = u + i;
        int e = idx & 7;
        int l = (idx >> 3) & 63;
        int f = (idx >> 9) & 31;
        int nc = idx >> 14;
        int n = nc * 32 + (l & 31);
        int k = f * 16 + (l >> 5) * 8 + e;
        WtF[idx] = f2bf(W[k * 512 + n]);
    }
}

// K0b: bias2p[b][n] = dec[b]·W_dec[:,n] + b_dec[n] + b_enc[n]
__global__ void k_bias2(const float* __restrict__ dec, const float* __restrict__ Wd,
                        const float* __restrict__ b_dec, const float* __restrict__ b_enc,
                        float* __restrict__ bias2p) {
    int blk = blockIdx.x;           // 256 blocks: b = blk>>2, nc = blk&3
    int b = blk >> 2, nc = blk & 3;
    int t = threadIdx.x;
    __shared__ float sdec[512];
    __shared__ float red[256];
    for (int k = t; k < 512; k += 256) sdec[k] = dec[b * 512 + k];
    __syncthreads();
    int n = nc * 128 + (t & 127);
    int kh = t >> 7;                // 0 or 1
    float acc = 0.f;
    int k0 = kh * 256;
    #pragma unroll 4
    for (int k = k0; k < k0 + 256; ++k)
        acc += sdec[k] * Wd[k * 512 + n];
    red[t] = acc;
    __syncthreads();
    if (t < 128) {
        int nn = nc * 128 + t;
        bias2p[b * 512 + nn] = red[t] + red[t + 128] + b_dec[nn] + b_enc[nn];
    }
}

// K1: fused enc@W_enc + bias -> relu -> ·W_full  =>  logits [B*L]
// 512 blocks x 256 thr (4 waves). Wave = 32 rows, FULL K resident in 32
// pinned A-frags (mfma_32x32x16). B streamed from global (frag-major WtF,
// perfectly coalesced, L1/L2-resident). NO LDS, NO barriers in the loop.
__global__ __launch_bounds__(256, 2) void k_logits(
        const float* __restrict__ enc, const unsigned short* __restrict__ WtF,
        const float* __restrict__ bias2p, const float* __restrict__ Wf,
        float* __restrict__ logits) {
    int t = threadIdx.x;
    int lane = t & 63;
    int w = t >> 6;                 // wave 0..3
    int blk = blockIdx.x;           // 512 blocks of 128 rows
    int row0 = blk * 128 + w * 32;  // this wave's 32 rows
    int b = blk >> 3;               // 8 blocks per batch
    int cl = lane & 31;             // A-row within tile / B-col within chunk
    int hf = lane >> 5;             // k-half (8 of 16)

    // A-frags: A[f] covers k in [f*16 + hf*8, +8) for row row0+cl
    bf16x8 A[32];
    {
        const float* ap = enc + (size_t)(row0 + cl) * 512 + hf * 8;
        #pragma unroll
        for (int f = 0; f < 32; ++f) {
            float4 x = *(const float4*)(ap + f * 16);
            float4 y = *(const float4*)(ap + f * 16 + 4);
            bf16x8 a;
            a[0] = (__bf16)x.x; a[1] = (__bf16)x.y; a[2] = (__bf16)x.z; a[3] = (__bf16)x.w;
            a[4] = (__bf16)y.x; a[5] = (__bf16)y.y; a[6] = (__bf16)y.z; a[7] = (__bf16)y.w;
            A[f] = a;
        }
    }
    // Pin A-frags: opaque defs -> no remat, stay resident (VGPR/AGPR).
    #pragma unroll
    for (int f = 0; f < 32; ++f)
        asm volatile("" : "+v"(A[f]));

    float p[16];
    #pragma unroll
    for (int r = 0; r < 16; ++r) p[r] = 0.f;

    const uint4* bbase = (const uint4*)WtF + lane;  // + (nc*32+f)*64

    for (int nc = 0; nc < 16; ++nc) {
        const uint4* bp = bbase + nc * 2048;
        f32x16 acc = {};
        // 4 groups of {8 loads, 8 mfma} — compiler pipelines across groups
        #pragma unroll
        for (int gq = 0; gq < 4; ++gq) {
            uint4 raw[8];
            #pragma unroll
            for (int j = 0; j < 8; ++j)
                raw[j] = bp[(gq * 8 + j) * 64];
            #pragma unroll
            for (int j = 0; j < 8; ++j) {
                bf16x8 bfr = __builtin_bit_cast(bf16x8, raw[j]);
                acc = __builtin_amdgcn_mfma_f32_32x32x16_bf16(A[gq * 8 + j], bfr, acc, 0, 0, 0);
            }
        }
        int col = nc * 32 + cl;
        float bias = bias2p[b * 512 + col];
        float wf = Wf[col];
        #pragma unroll
        for (int r = 0; r < 16; ++r) {
            float v = acc[r] + bias;
            v = v > 0.f ? v : 0.f;
            p[r] += v * wf;
        }
    }

    // reduce over 32 cols (lanes within each 32-half); then lane cl==0 writes
    #pragma unroll
    for (int r = 0; r < 16; ++r) {
        float v = p[r];
        v += __shfl_xor(v, 1, 64);
        v += __shfl_xor(v, 2, 64);
        v += __shfl_xor(v, 4, 64);
        v += __shfl_xor(v, 8, 64);
        v += __shfl_xor(v, 16, 64);
        if (cl == 0)
            logits[row0 + (r & 3) + 8 * (r >> 2) + 4 * hf] = v;
    }
}

// K2: softmax over L per batch (b_full omitted: softmax is shift-invariant)
__global__ void k_softmax(const float* __restrict__ logits, float* __restrict__ alpha) {
    int b = blockIdx.x;
    int t = threadIdx.x;
    __shared__ float red[256];
    float4 v = ((const float4*)(logits + b * 1024))[t];
    float mx = fmaxf(fmaxf(v.x, v.y), fmaxf(v.z, v.w));
    red[t] = mx;
    __syncthreads();
    for (int s = 128; s > 0; s >>= 1) {
        if (t < s) red[t] = fmaxf(red[t], red[t + s]);
        __syncthreads();
    }
    mx = red[0];
    __syncthreads();
    float4 e;
    e.x = expf(v.x - mx); e.y = expf(v.y - mx);
    e.z = expf(v.z - mx); e.w = expf(v.w - mx);
    red[t] = e.x + e.y + e.z + e.w;
    __syncthreads();
    for (int s = 128; s > 0; s >>= 1) {
        if (t < s) red[t] += red[t + s];
        __syncthreads();
    }
    float inv = 1.0f / red[0];
    float4 o;
    o.x = e.x * inv; o.y = e.y * inv; o.z = e.z * inv; o.w = e.w * inv;
    ((float4*)(alpha + b * 1024))[t] = o;
}

// K3: partial weighted sums over l-chunks of 128 (float4 loads, 16B/lane)
__global__ void k_wsum_part(const float* __restrict__ enc, const float* __restrict__ alpha,
                            float* __restrict__ part) {
    int blk = blockIdx.x;           // 512 blocks: b = blk>>3, chunk c = blk&7
    int b = blk >> 3, c = blk & 7;
    int t = threadIdx.x;
    int col = (t & 127) * 4;
    int lh = t >> 7;                // 0/1: which l-parity
    const float* ep = enc + (size_t)(b * 1024 + c * 128) * 512;
    const float* al = alpha + b * 1024 + c * 128;
    float4 s = {0.f, 0.f, 0.f, 0.f};
    #pragma unroll 4
    for (int i = 0; i < 64; ++i) {
        int l = i * 2 + lh;
        float a = al[l];
        float4 e = *(const float4*)(ep + (size_t)l * 512 + col);
        s.x += e.x * a; s.y += e.y * a; s.z += e.z * a; s.w += e.w * a;
    }
    __shared__ float red[2][512];
    *(float4*)&red[lh][col] = s;
    __syncthreads();
    if (t < 128) {
        float4 a0 = *(const float4*)&red[0][t * 4];
        float4 a1 = *(const float4*)&red[1][t * 4];
        float4 o;
        o.x = a0.x + a1.x; o.y = a0.y + a1.y;
        o.z = a0.z + a1.z; o.w = a0.w + a1.w;
        *(float4*)(part + (size_t)blk * 512 + t * 4) = o;
    }
}

// K4: reduce 8 partials -> attn_weighted_enc (128 thr, float4)
__global__ void k_wsum_final(const float* __restrict__ part, float* __restrict__ out) {
    int b = blockIdx.x;
    int t = threadIdx.x;
    float4 s = {0.f, 0.f, 0.f, 0.f};
    #pragma unroll
    for (int c = 0; c < 8; ++c) {
        float4 v = *(const float4*)(part + (size_t)(b * 8 + c) * 512 + t * 4);
        s.x += v.x; s.y += v.y; s.z += v.z; s.w += v.w;
    }
    *(float4*)(out + b * 512 + t * 4) = s;
}

extern "C" void kernel_launch(void* const* d_in, const int* in_sizes, int n_in,
                              void* d_out, int out_size, void* d_ws, size_t ws_size,
                              hipStream_t stream) {
    const float* enc    = (const float*)d_in[0];  // [64,1024,512]
    const float* dec    = (const float*)d_in[1];  // [64,512]
    const float* W_enc  = (const float*)d_in[2];  // [512,512]
    const float* b_enc  = (const float*)d_in[3];  // [512]
    const float* W_dec  = (const float*)d_in[4];  // [512,512]
    const float* b_dec  = (const float*)d_in[5];  // [512]
    const float* W_full = (const float*)d_in[6];  // [512]
    // d_in[7] = b_full: unused (softmax is shift-invariant)

    float* out = (float*)d_out;                   // [0,32768) weighted enc; [32768,98304) alpha
    char* ws = (char*)d_ws;
    unsigned short* WtF = (unsigned short*)(ws + WS_WT);
    float* bias2p = (float*)(ws + WS_BIAS);
    float* logits = (float*)(ws + WS_LOGITS);
    float* part   = (float*)(ws + WS_PART);
    float* alpha  = out + 32768;

    hipLaunchKernelGGL(k_wt,         dim3(256),  dim3(256), 0, stream, W_enc, WtF);
    hipLaunchKernelGGL(k_bias2,      dim3(256),  dim3(256), 0, stream, dec, W_dec, b_dec, b_enc, bias2p);
    hipLaunchKernelGGL(k_logits,     dim3(512),  dim3(256), 0, stream, enc, WtF, bias2p, W_full, logits);
    hipLaunchKernelGGL(k_softmax,    dim3(64),   dim3(256), 0, stream, logits, alpha);
    hipLaunchKernelGGL(k_wsum_part,  dim3(512),  dim3(256), 0, stream, enc, alpha, part);
    hipLaunchKernelGGL(k_wsum_final, dim3(64),   dim3(128), 0, stream, part, out);
}

// Round 6
// 105.807 us; speedup vs baseline: 1.3556x; 1.3556x over previous
//
#include <hip/hip_runtime.h>
#include <hip/hip_bf16.h>

typedef __bf16 bf16x8 __attribute__((ext_vector_type(8)));
typedef float f32x4 __attribute__((ext_vector_type(4)));
typedef unsigned int u32;
typedef unsigned short u16;

// ws layout (bytes):
//   [0,        524288)  WtP   : bf16 W_enc pack [ks=16][c=32][m=16][g=4][e=8]
//   [524288,   655360)  bias2p: f32 [64][512]  (attn2 + b_dec + b_enc)
//   [655360,   917504)  logits: f32 [65536]
//   [917504,  1966080)  part  : f32 [64][8][512]
#define WS_WT     0
#define WS_BIAS   524288
#define WS_LOGITS 655360
#define WS_PART   917504

__device__ __forceinline__ u16 f2bf(float f) {
    __bf16 h = (__bf16)f;
    return __builtin_bit_cast(u16, h);
}

__device__ __forceinline__ void gload_lds16(const void* g, void* l) {
    __builtin_amdgcn_global_load_lds(
        (const __attribute__((address_space(1))) u32*)g,
        (__attribute__((address_space(3))) u32*)l, 16, 0, 0);
}

// K0a: pack W_enc -> WtP unit u (16B): u = ((ks*32+c)*16+m)*4+g,
// holds W[k][n] for n = c*16+m, k = ks*32+g*8+e (e=0..7)
__global__ void k_wt(const float* __restrict__ W, u16* __restrict__ WtP) {
    int u = blockIdx.x * 256 + threadIdx.x;     // 32768 units
    int g = u & 3, m = (u >> 2) & 15, c = (u >> 6) & 31, ks = u >> 11;
    int n = c * 16 + m;
    int k0 = ks * 32 + g * 8;
    u16 out[8];
    #pragma unroll
    for (int e = 0; e < 8; ++e)
        out[e] = f2bf(W[(k0 + e) * 512 + n]);
    *(uint4*)(WtP + (size_t)u * 8) = *(const uint4*)out;
}

// K0b: bias2p[b][n] = dec[b]·W_dec[:,n] + b_dec[n] + b_enc[n]
__global__ void k_bias2(const float* __restrict__ dec, const float* __restrict__ Wd,
                        const float* __restrict__ b_dec, const float* __restrict__ b_enc,
                        float* __restrict__ bias2p) {
    int blk = blockIdx.x;           // 256 blocks: b = blk>>2, nc = blk&3
    int b = blk >> 2, nc = blk & 3;
    int t = threadIdx.x;
    __shared__ float sdec[512];
    __shared__ float red[256];
    for (int k = t; k < 512; k += 256) sdec[k] = dec[b * 512 + k];
    __syncthreads();
    int n = nc * 128 + (t & 127);
    int kh = t >> 7;
    float acc = 0.f;
    int k0 = kh * 256;
    #pragma unroll 4
    for (int k = k0; k < k0 + 256; ++k)
        acc += sdec[k] * Wd[k * 512 + n];
    red[t] = acc;
    __syncthreads();
    if (t < 128) {
        int nn = nc * 128 + t;
        bias2p[b * 512 + nn] = red[t] + red[t + 128] + b_dec[nn] + b_enc[nn];
    }
}

// K1: fused enc@W_enc + bias -> relu -> ·W_full  =>  logits [B*L]
// 512 blocks x 512 thr (8 waves, 2x4). Block = 128 rows x ALL 512 cols.
// Wave tile 64x128: acc[4][8] f32x4. K-loop 16 steps of 32:
//  A: reg-staged fp32->bf16 -> LDS (8KB/step, dbuf), B: global_load_lds from
//  WtP (32KB/step, dbuf). ONE raw s_barrier + counted vmcnt(6) per step.
__global__ __launch_bounds__(512, 1) void k_logits(
        const float* __restrict__ enc, const u16* __restrict__ WtP,
        const float* __restrict__ bias2p, const float* __restrict__ Wf,
        float* __restrict__ logits) {
    __shared__ __align__(16) char ldsB[2][32768];
    __shared__ __align__(16) char ldsA[2][8192];
    __shared__ float comb[4][128];

    int t = threadIdx.x;
    int lane = t & 63;
    int w = t >> 6;                 // wave 0..7
    int wm = w >> 2;                // 0..1 (row half)
    int wn = w & 3;                 // 0..3 (col quarter)
    int m = lane & 15;
    int g = lane >> 4;
    int blk = blockIdx.x;           // 512 blocks of 128 rows
    int b = blk >> 3;

    // A-stage mapping for this thread: row-in-block = t>>2, k-slot = t&3
    const float* aptr = enc + (size_t)(blk * 128 + (t >> 2)) * 512 + (t & 3) * 8;

    // stage B for k-step ks_ into ldsB[bufi]: wave w stages units [(w*4+j)*64 + lane]
    #define STAGEB(bufi, ks_)                                                     \
        {                                                                         \
            const char* src_ = (const char*)WtP + (size_t)(ks_) * 32768           \
                               + (size_t)(w * 4 * 64 + lane) * 16;                \
            char* dst_ = &ldsB[bufi][w * 4 * 1024];                               \
            _Pragma("unroll")                                                     \
            for (int j = 0; j < 4; ++j)                                           \
                gload_lds16(src_ + j * 1024, dst_ + j * 1024);                    \
        }

    // prologue: stage k-step 0 (B via DMA, A via regs)
    STAGEB(0, 0)
    {
        float4 v0 = *(const float4*)(aptr);
        float4 v1 = *(const float4*)(aptr + 4);
        u16 pk[8];
        pk[0] = f2bf(v0.x); pk[1] = f2bf(v0.y); pk[2] = f2bf(v0.z); pk[3] = f2bf(v0.w);
        pk[4] = f2bf(v1.x); pk[5] = f2bf(v1.y); pk[6] = f2bf(v1.z); pk[7] = f2bf(v1.w);
        *(uint4*)&ldsA[0][t * 16] = *(const uint4*)pk;
    }
    asm volatile("s_waitcnt lgkmcnt(0)" ::: "memory");

    f32x4 acc[4][8];
    #pragma unroll
    for (int mt = 0; mt < 4; ++mt)
        #pragma unroll
        for (int nt = 0; nt < 8; ++nt)
            acc[mt][nt] = (f32x4){0.f, 0.f, 0.f, 0.f};

    for (int ks = 0; ks < 16; ++ks) {
        int buf = ks & 1;
        __builtin_amdgcn_s_barrier();   // prev step's reads done; this step's LDS visible
        float4 av0, av1;
        if (ks < 15) {
            STAGEB(buf ^ 1, ks + 1)
            av0 = *(const float4*)(aptr + (ks + 1) * 32);
            av1 = *(const float4*)(aptr + (ks + 1) * 32 + 4);
            __builtin_amdgcn_sched_barrier(0);
            asm volatile("s_waitcnt vmcnt(6)" ::: "memory");   // B(ks) landed; 6 in flight
        } else {
            asm volatile("s_waitcnt vmcnt(0)" ::: "memory");   // last step: drain B(15)
        }
        __builtin_amdgcn_sched_barrier(0);

        // fragment reads (dense 1KB per tile-group -> conflict-free)
        bf16x8 Af[4];
        uint4 Br[8];
        #pragma unroll
        for (int mt = 0; mt < 4; ++mt)
            Af[mt] = *(const bf16x8*)&ldsA[buf][((wm * 4 + mt) * 64 + m * 4 + g) * 16];
        #pragma unroll
        for (int nt = 0; nt < 8; ++nt)
            Br[nt] = *(const uint4*)&ldsB[buf][((wn * 8 + nt) * 64 + m * 4 + g) * 16];
        #pragma unroll
        for (int mt = 0; mt < 4; ++mt)
            #pragma unroll
            for (int nt = 0; nt < 8; ++nt)
                acc[mt][nt] = __builtin_amdgcn_mfma_f32_16x16x32_bf16(
                    Af[mt], __builtin_bit_cast(bf16x8, Br[nt]), acc[mt][nt], 0, 0, 0);

        if (ks < 15) {               // A(ks+1): cvt + LDS write (latency hidden under MFMAs)
            u16 pk[8];
            pk[0] = f2bf(av0.x); pk[1] = f2bf(av0.y); pk[2] = f2bf(av0.z); pk[3] = f2bf(av0.w);
            pk[4] = f2bf(av1.x); pk[5] = f2bf(av1.y); pk[6] = f2bf(av1.z); pk[7] = f2bf(av1.w);
            *(uint4*)&ldsA[buf ^ 1][t * 16] = *(const uint4*)pk;
        }
        asm volatile("s_waitcnt lgkmcnt(0)" ::: "memory");
    }

    // epilogue: relu(acc + bias)·Wf, reduce over cols
    float p[4][4];
    #pragma unroll
    for (int mt = 0; mt < 4; ++mt)
        #pragma unroll
        for (int r = 0; r < 4; ++r) p[mt][r] = 0.f;

    #pragma unroll
    for (int nt = 0; nt < 8; ++nt) {
        int col = wn * 128 + nt * 16 + m;
        float bias = bias2p[b * 512 + col];
        float wfv = Wf[col];
        #pragma unroll
        for (int mt = 0; mt < 4; ++mt) {
            #pragma unroll
            for (int r = 0; r < 4; ++r) {
                float v = acc[mt][nt][r] + bias;
                v = v > 0.f ? v : 0.f;
                p[mt][r] += v * wfv;
            }
        }
    }

    #pragma unroll
    for (int mt = 0; mt < 4; ++mt) {
        #pragma unroll
        for (int r = 0; r < 4; ++r) {
            float v = p[mt][r];
            v += __shfl_xor(v, 1, 64);
            v += __shfl_xor(v, 2, 64);
            v += __shfl_xor(v, 4, 64);
            v += __shfl_xor(v, 8, 64);
            if (m == 0)
                comb[wn][wm * 64 + mt * 16 + g * 4 + r] = v;
        }
    }
    __syncthreads();
    if (t < 128)
        logits[blk * 128 + t] = comb[0][t] + comb[1][t] + comb[2][t] + comb[3][t];
}

// K2: softmax over L per batch (b_full omitted: softmax is shift-invariant)
__global__ void k_softmax(const float* __restrict__ logits, float* __restrict__ alpha) {
    int b = blockIdx.x;
    int t = threadIdx.x;
    __shared__ float red[256];
    float4 v = ((const float4*)(logits + b * 1024))[t];
    float mx = fmaxf(fmaxf(v.x, v.y), fmaxf(v.z, v.w));
    red[t] = mx;
    __syncthreads();
    for (int s = 128; s > 0; s >>= 1) {
        if (t < s) red[t] = fmaxf(red[t], red[t + s]);
        __syncthreads();
    }
    mx = red[0];
    __syncthreads();
    float4 e;
    e.x = expf(v.x - mx); e.y = expf(v.y - mx);
    e.z = expf(v.z - mx); e.w = expf(v.w - mx);
    red[t] = e.x + e.y + e.z + e.w;
    __syncthreads();
    for (int s = 128; s > 0; s >>= 1) {
        if (t < s) red[t] += red[t + s];
        __syncthreads();
    }
    float inv = 1.0f / red[0];
    float4 o;
    o.x = e.x * inv; o.y = e.y * inv; o.z = e.z * inv; o.w = e.w * inv;
    ((float4*)(alpha + b * 1024))[t] = o;
}

// K3: partial weighted sums over l-chunks of 128 (float4 loads, 16B/lane)
__global__ void k_wsum_part(const float* __restrict__ enc, const float* __restrict__ alpha,
                            float* __restrict__ part) {
    int blk = blockIdx.x;           // 512 blocks: b = blk>>3, chunk c = blk&7
    int b = blk >> 3, c = blk & 7;
    int t = threadIdx.x;
    int col = (t & 127) * 4;
    int lh = t >> 7;
    const float* ep = enc + (size_t)(b * 1024 + c * 128) * 512;
    const float* al = alpha + b * 1024 + c * 128;
    float4 s = {0.f, 0.f, 0.f, 0.f};
    #pragma unroll 4
    for (int i = 0; i < 64; ++i) {
        int l = i * 2 + lh;
        float a = al[l];
        float4 e = *(const float4*)(ep + (size_t)l * 512 + col);
        s.x += e.x * a; s.y += e.y * a; s.z += e.z * a; s.w += e.w * a;
    }
    __shared__ float red[2][512];
    *(float4*)&red[lh][col] = s;
    __syncthreads();
    if (t < 128) {
        float4 a0 = *(const float4*)&red[0][t * 4];
        float4 a1 = *(const float4*)&red[1][t * 4];
        float4 o;
        o.x = a0.x + a1.x; o.y = a0.y + a1.y;
        o.z = a0.z + a1.z; o.w = a0.w + a1.w;
        *(float4*)(part + (size_t)blk * 512 + t * 4) = o;
    }
}

// K4: reduce 8 partials -> attn_weighted_enc (128 thr, float4)
__global__ void k_wsum_final(const float* __restrict__ part, float* __restrict__ out) {
    int b = blockIdx.x;
    int t = threadIdx.x;
    float4 s = {0.f, 0.f, 0.f, 0.f};
    #pragma unroll
    for (int c = 0; c < 8; ++c) {
        float4 v = *(const float4*)(part + (size_t)(b * 8 + c) * 512 + t * 4);
        s.x += v.x; s.y += v.y; s.z += v.z; s.w += v.w;
    }
    *(float4*)(out + b * 512 + t * 4) = s;
}

extern "C" void kernel_launch(void* const* d_in, const int* in_sizes, int n_in,
                              void* d_out, int out_size, void* d_ws, size_t ws_size,
                              hipStream_t stream) {
    const float* enc    = (const float*)d_in[0];  // [64,1024,512]
    const float* dec    = (const float*)d_in[1];  // [64,512]
    const float* W_enc  = (const float*)d_in[2];  // [512,512]
    const float* b_enc  = (const float*)d_in[3];  // [512]
    const float* W_dec  = (const float*)d_in[4];  // [512,512]
    const float* b_dec  = (const float*)d_in[5];  // [512]
    const float* W_full = (const float*)d_in[6];  // [512]
    // d_in[7] = b_full: unused (softmax is shift-invariant)

    float* out = (float*)d_out;                   // [0,32768) weighted enc; [32768,98304) alpha
    char* ws = (char*)d_ws;
    u16* WtP      = (u16*)(ws + WS_WT);
    float* bias2p = (float*)(ws + WS_BIAS);
    float* logits = (float*)(ws + WS_LOGITS);
    float* part   = (float*)(ws + WS_PART);
    float* alpha  = out + 32768;

    hipLaunchKernelGGL(k_wt,         dim3(128),  dim3(256), 0, stream, W_enc, WtP);
    hipLaunchKernelGGL(k_bias2,      dim3(256),  dim3(256), 0, stream, dec, W_dec, b_dec, b_enc, bias2p);
    hipLaunchKernelGGL(k_logits,     dim3(512),  dim3(512), 0, stream, enc, WtP, bias2p, W_full, logits);
    hipLaunchKernelGGL(k_softmax,    dim3(64),   dim3(256), 0, stream, logits, alpha);
    hipLaunchKernelGGL(k_wsum_part,  dim3(512),  dim3(256), 0, stream, enc, alpha, part);
    hipLaunchKernelGGL(k_wsum_final, dim3(64),   dim3(128), 0, stream, part, out);
}